// Round 3
// baseline (770.741 us; speedup 1.0000x reference)
//
#include <hip/hip_runtime.h>
#include <hip/hip_cooperative_groups.h>
#include <math.h>

namespace cg = cooperative_groups;

#define B_ 16
#define H_ 16
#define M_ 256
#define N_ 576
#define D_ 1024
#define NROWS (B_ * N_ + B_ * M_)                  // 13312 feature rows
#define SL_UNITS (B_ * M_ * N_ / 4)                // 589824 float4 columns
#define GEMM_TILES (B_ * (M_ / 64) * (N_ / 64))    // 576 tiles
#define NPHASE 14

constexpr float EPS_ = 1e-8f;
constexpr float FI_ = 0.90909090909090906f;   // RHO/(RHO+EPSILON) = 1/1.1

typedef __bf16 bf16x8 __attribute__((ext_vector_type(8)));
typedef float f32x4 __attribute__((ext_vector_type(4)));

__device__ __forceinline__ float wave_reduce(float v) {
#pragma unroll
  for (int o = 32; o > 0; o >>= 1) v += __shfl_down(v, o, 64);
  return v;
}

__device__ __forceinline__ unsigned short f2bf(float f) {
  union { float f; unsigned u; } a; a.f = f;
  unsigned r = a.u + 0x7fff + ((a.u >> 16) & 1);   // RNE
  return (unsigned short)(r >> 16);
}

__device__ __forceinline__ float bf2f(unsigned short u) {
  union { unsigned u; float f; } a; a.u = ((unsigned)u) << 16;
  return a.f;
}

// Phases (grid.sync between consecutive phases when run cooperatively):
//  0: prep  (L2-normalize feats -> bf16; masksum)
//  1: gemm  K = bf16(exp(10*(y.x - 1))), 64x64 tile/block, 8 waves
//  2..11: sink steps (even=u, odd=v), each also streams 1/10 of sumlog
//  12: finloss per (b,m) row
//  13: reduce 4096 partials -> out
// All per-output summation orders are bit-identical to the verified split
// kernels (absmax 0.0 lineage).
__global__ __launch_bounds__(512, 4) void mega_kernel(
    const float* __restrict__ student, const float* __restrict__ vis,
    const float* __restrict__ txt, const float* __restrict__ mask,
    unsigned short* __restrict__ xb, unsigned short* __restrict__ yb,
    unsigned short* __restrict__ Kw, float* __restrict__ SL,
    float* __restrict__ uu, float* __restrict__ vv,
    float* __restrict__ msum, float* __restrict__ partial,
    float* __restrict__ out, int plo, int phi) {
  __shared__ unsigned short As[64][72];
  __shared__ unsigned short Bs[64][72];
  __shared__ float part[4][64];
  __shared__ float redf[2][2][4];
  __shared__ float redr[4];

  const int tid = threadIdx.x;     // 0..511
  const int lane = tid & 63;
  const int w = tid >> 6;          // wave 0..7
  const int bid = blockIdx.x;
  const int GRID = gridDim.x;

  for (int ph = plo; ph < phi; ++ph) {
    if (ph > plo) cg::this_grid().sync();

    if (ph == 0) {
      // ---- prep: one wave per feature row; rows NROWS.. are mask sums ----
      for (int row = bid * 8 + w; row < NROWS + B_; row += GRID * 8) {
        if (row < NROWS) {
          const float* src;
          unsigned short* dst;
          if (row < B_ * N_) {
            src = vis + (size_t)row * D_;
            dst = xb + (size_t)row * D_;
          } else {
            int r = row - B_ * N_;
            src = txt + (size_t)r * D_;
            dst = yb + (size_t)r * D_;
          }
          float4 v[4];
          float s = 0.f;
#pragma unroll
          for (int it = 0; it < 4; ++it) {
            v[it] = *(const float4*)&src[it * 256 + lane * 4];
            s += v[it].x * v[it].x + v[it].y * v[it].y + v[it].z * v[it].z + v[it].w * v[it].w;
          }
          s = wave_reduce(s);
          s = __shfl(s, 0, 64);
          float inv = rsqrtf(s + 1e-12f);
#pragma unroll
          for (int it = 0; it < 4; ++it) {
            ushort4 pk;
            pk.x = f2bf(v[it].x * inv);
            pk.y = f2bf(v[it].y * inv);
            pk.z = f2bf(v[it].z * inv);
            pk.w = f2bf(v[it].w * inv);
            *(ushort4*)&dst[it * 256 + lane * 4] = pk;
          }
        } else {
          int b = row - NROWS;
          float4 mv = *(const float4*)&mask[b * M_ + lane * 4];
          float s = wave_reduce(mv.x + mv.y + mv.z + mv.w);
          if (lane == 0) msum[b] = s;
        }
      }

    } else if (ph == 1) {
      // ---- gemm: 64x64 tile per block, 8 waves (4 m-quadrants x 2 n-halves).
      // Per-output MFMA accumulation chain identical to the verified kernel.
      const int lr = tid >> 3;
      const int lc = (tid & 7) * 8;
      const int am = (w & 3) * 16;
      const int wn = (w >> 2) * 32;
      const int fr = lane & 15;
      const int fk = (lane >> 4) * 8;
      const int cm = (lane >> 4) * 4;
      const int cn = lane & 15;
      for (int tt = bid; tt < GEMM_TILES; tt += GRID) {
        const int b = tt / 36;
        const int rem = tt - b * 36;
        const int m0 = (rem / 9) * 64;
        const int n0 = (rem - (rem / 9) * 9) * 64;
        const unsigned short* Y = yb + (size_t)b * M_ * D_;
        const unsigned short* X = xb + (size_t)b * N_ * D_;
        f32x4 acc[2] = {};
        for (int k0 = 0; k0 < D_; k0 += 64) {
          __syncthreads();
          *(uint4*)&As[lr][lc] = *(const uint4*)&Y[(size_t)(m0 + lr) * D_ + k0 + lc];
          *(uint4*)&Bs[lr][lc] = *(const uint4*)&X[(size_t)(n0 + lr) * D_ + k0 + lc];
          __syncthreads();
#pragma unroll
          for (int ks = 0; ks < 64; ks += 32) {
            bf16x8 a = *(const bf16x8*)&As[am + fr][ks + fk];
            bf16x8 b0 = *(const bf16x8*)&Bs[wn + fr][ks + fk];
            bf16x8 b1 = *(const bf16x8*)&Bs[wn + 16 + fr][ks + fk];
            acc[0] = __builtin_amdgcn_mfma_f32_16x16x32_bf16(a, b0, acc[0], 0, 0, 0);
            acc[1] = __builtin_amdgcn_mfma_f32_16x16x32_bf16(a, b1, acc[1], 0, 0, 0);
          }
        }
#pragma unroll
        for (int j = 0; j < 2; ++j)
#pragma unroll
          for (int rg = 0; rg < 4; ++rg) {
            int m = m0 + am + cm + rg;
            int n = n0 + wn + j * 16 + cn;
            Kw[((size_t)b * M_ + m) * N_ + n] = f2bf(expf(10.f * (acc[j][rg] - 1.f)));
          }
      }

    } else if (ph < 12) {
      const int sp = ph - 2;   // 0,2,4,6,8 = u-steps; 1,3,5,7,9 = v-steps
      if ((sp & 1) == 0) {
        // ---- u-step: one (b,m) row per wave; sp==0 uses v==1 ----
        for (int row = bid * 8 + w; row < B_ * M_; row += GRID * 8) {
          const unsigned short* rp = Kw + (size_t)row * N_;
          float s = 0.f;
          if (sp == 0) {
#pragma unroll
            for (int k = 0; k < 9; ++k) s += bf2f(rp[lane + 64 * k]);
          } else {
            const float* vb = vv + (row >> 8) * N_;
#pragma unroll
            for (int k = 0; k < 9; ++k) s += bf2f(rp[lane + 64 * k]) * vb[lane + 64 * k];
          }
          s = wave_reduce(s);
          if (lane == 0) {
            float nu = mask[row] / (msum[row >> 8] + EPS_);
            uu[row] = powf(nu / (s + EPS_), FI_);
          }
        }
      } else {
        // ---- v-step: unit = (b, n0/64); waves 0..3 do row-quarters ----
        for (int unit = bid; unit < B_ * (N_ / 64); unit += GRID) {
          const int b = unit / 9;
          const int n0 = (unit - b * 9) * 64;
          const unsigned short* Kb2 = Kw + (size_t)b * M_ * N_;
          const float* ub = uu + b * M_;
          if (w < 4) {
            const int col = n0 + lane;
            float s = 0.f;
#pragma unroll 8
            for (int m = w * 64; m < (w + 1) * 64; ++m)
              s += bf2f(Kb2[(size_t)m * N_ + col]) * ub[m];
            part[w][lane] = s;
          }
          __syncthreads();
          if (tid < 64) {
            float tot = part[0][tid] + part[1][tid] + part[2][tid] + part[3][tid];
            vv[b * N_ + n0 + tid] = powf((1.f / (float)N_) / (tot + EPS_), FI_);
          }
          __syncthreads();
        }
      }
      // ---- sumlog chunk sp: 1/10 of the 151 MB student stream, overlapped.
      // Rotating block assignment spreads HBM work away from v-step blocks.
      {
        const int c0 = (int)(((long long)SL_UNITS * sp) / 10);
        const int c1 = (int)(((long long)SL_UNITS * (sp + 1)) / 10);
        const int nblk = (c1 - c0 + 511) >> 9;
        const int rb = (bid + (sp * GRID) / 10) % GRID;
        if (rb < nblk) {
          const int u = c0 + (rb << 9) + tid;
          if (u < c1) {
            const int b = u / (M_ * N_ / 4);
            const int cb = u - b * (M_ * N_ / 4);
            const float* st = student + (size_t)b * H_ * M_ * N_ + (size_t)cb * 4;
            float4 acc = {0.f, 0.f, 0.f, 0.f};
#pragma unroll
            for (int h = 0; h < H_; ++h) {
              float4 s4 = *(const float4*)&st[(size_t)h * M_ * N_];
              acc.x += __logf(s4.x + EPS_);
              acc.y += __logf(s4.y + EPS_);
              acc.z += __logf(s4.z + EPS_);
              acc.w += __logf(s4.w + EPS_);
            }
            *(float4*)&SL[(size_t)b * M_ * N_ + (size_t)cb * 4] = acc;
          }
        }
      }

    } else if (ph == 12) {
      // ---- finloss: one (b,m) unit per 4-wave half-block ----
      const int half = tid >> 8;
      const int lt = tid & 255;
      const int stride = GRID * 2;
      // Same iteration count for both halves (4096 mod stride is even),
      // so block-wide barriers stay aligned.
      const int cnt = (B_ * M_ - 1 - bid * 2) / stride + 1;
      for (int i = 0; i < cnt; ++i) {
        const int unit = bid * 2 + half + i * stride;
        float s1 = 0.f, s2 = 0.f;
        if (unit < B_ * M_ && lt < 144) {
          const int b = unit >> 8;
          const unsigned short* kp = Kw + (size_t)unit * N_ + lt * 4;
          ushort4 k4 = *(const ushort4*)kp;
          float4 v4 = *(const float4*)&vv[b * N_ + lt * 4];
          float4 sl4 = *(const float4*)&SL[(size_t)unit * N_ + lt * 4];
          float kv0 = bf2f(k4.x) * v4.x, kv1 = bf2f(k4.y) * v4.y;
          float kv2 = bf2f(k4.z) * v4.z, kv3 = bf2f(k4.w) * v4.w;
          s1 = kv0 + kv1 + kv2 + kv3;
          s2 = kv0 * sl4.x + kv1 * sl4.y + kv2 * sl4.z + kv3 * sl4.w;
        }
        s1 = wave_reduce(s1);
        s2 = wave_reduce(s2);
        if ((lt & 63) == 0) { redf[half][0][lt >> 6] = s1; redf[half][1][lt >> 6] = s2; }
        __syncthreads();
        if (lt == 0 && unit < B_ * M_) {
          float S1 = redf[half][0][0] + redf[half][0][1] + redf[half][0][2] + redf[half][0][3];
          float S2 = redf[half][1][0] + redf[half][1][1] + redf[half][1][2] + redf[half][1][3];
          partial[unit] = -mask[unit] * S2 / ((S1 + EPS_) * (float)(B_ * H_ * M_));
        }
        __syncthreads();
      }

    } else {
      // ---- reduce: block 0, threads 0..255 (identical order) ----
      if (bid == 0) {
        float s = 0.f;
        if (tid < 256)
          for (int i = tid; i < B_ * M_; i += 256) s += partial[i];
        s = wave_reduce(s);
        if (tid < 256 && (tid & 63) == 0) redr[tid >> 6] = s;
        __syncthreads();
        if (tid == 0) out[0] = redr[0] + redr[1] + redr[2] + redr[3];
      }
    }
  }
}

extern "C" void kernel_launch(void* const* d_in, const int* in_sizes, int n_in,
                              void* d_out, int out_size, void* d_ws, size_t ws_size,
                              hipStream_t stream) {
  const float* student = (const float*)d_in[0];  // (B,H,M,N)
  const float* vis = (const float*)d_in[1];      // (B,N,D)
  const float* txt = (const float*)d_in[2];      // (B,M,D)
  const float* mask = (const float*)d_in[3];     // (B,M)
  float* out = (float*)d_out;

  char* p = (char*)d_ws;
  unsigned short* Kw = (unsigned short*)p; p += (size_t)B_ * M_ * N_ * 2;   // 4.7 MB
  unsigned short* xb = (unsigned short*)p; p += (size_t)B_ * N_ * D_ * 2;   // 18.9 MB
  unsigned short* yb = (unsigned short*)p; p += (size_t)B_ * M_ * D_ * 2;   // 8.4 MB
  float* SL = (float*)p;      p += (size_t)B_ * M_ * N_ * 4;                // 9.4 MB
  float* vv = (float*)p;      p += B_ * N_ * 4;
  float* uu = (float*)p;      p += B_ * M_ * 4;
  float* msum = (float*)p;    p += B_ * 4;
  float* partial = (float*)p; p += B_ * M_ * 4;

  // One-time host-side capability check (no stream ops; graph-capture-safe).
  static int coop_blocks = -2;
  if (coop_blocks == -2) {
    int dev = 0;
    (void)hipGetDevice(&dev);
    int has_coop = 0;
    (void)hipDeviceGetAttribute(&has_coop, hipDeviceAttributeCooperativeLaunch, dev);
    int nb = 0;
    hipError_t e = hipOccupancyMaxActiveBlocksPerMultiprocessor(
        &nb, reinterpret_cast<const void*>(&mega_kernel), 512, 0);
    coop_blocks = (has_coop && e == hipSuccess && nb >= 1) ? nb : 0;
  }

  bool launched = false;
  if (coop_blocks > 0) {
    int grid = coop_blocks * 256;
    if (grid > 512) grid = 512;
    int plo = 0, phi = NPHASE;
    void* args[] = {(void*)&student, (void*)&vis,  (void*)&txt,  (void*)&mask,
                    (void*)&xb,      (void*)&yb,   (void*)&Kw,   (void*)&SL,
                    (void*)&uu,      (void*)&vv,   (void*)&msum, (void*)&partial,
                    (void*)&out,     (void*)&plo,  (void*)&phi};
    hipError_t e = hipLaunchCooperativeKernel(
        reinterpret_cast<const void*>(&mega_kernel), dim3(grid), dim3(512),
        args, 0, stream);
    launched = (e == hipSuccess);
  }
  if (!launched) {
    // Fallback: phases as separate launches; kernel boundaries provide the
    // grid-wide sync (phi = plo+1 means grid.sync() is never executed).
    for (int ph2 = 0; ph2 < NPHASE; ++ph2)
      mega_kernel<<<dim3(512), dim3(512), 0, stream>>>(
          student, vis, txt, mask, xb, yb, Kw, SL, uu, vv, msum, partial, out,
          ph2, ph2 + 1);
  }
}

// Round 4
// 424.576 us; speedup vs baseline: 1.8153x; 1.8153x over previous
//
#include <hip/hip_runtime.h>
#include <math.h>

#define B_ 16
#define H_ 16
#define M_ 256
#define N_ 576
#define D_ 1024
#define BK 64
#define LDS_STRIDE (BK + 8)
#define NROWS (B_ * N_ + B_ * M_)         // 13312 feature rows
#define SL_UNITS (B_ * M_ * N_ / 4)       // 589824 float4 units
#define GEMM_BLOCKS (B_ * 4 * 9)          // 576 tiles
#define SUMLOG_BLK (SL_UNITS / 256)       // 2304

constexpr float EPS_ = 1e-8f;
constexpr float FI_ = 0.90909090909090906f;   // RHO/(RHO+EPSILON) = 1/1.1

typedef __bf16 bf16x8 __attribute__((ext_vector_type(8)));
typedef float f32x4 __attribute__((ext_vector_type(4)));

__device__ __forceinline__ float wave_reduce(float v) {
#pragma unroll
  for (int o = 32; o > 0; o >>= 1) v += __shfl_down(v, o, 64);
  return v;
}

__device__ __forceinline__ unsigned short f2bf(float f) {
  union { float f; unsigned u; } a; a.f = f;
  unsigned r = a.u + 0x7fff + ((a.u >> 16) & 1);   // RNE
  return (unsigned short)(r >> 16);
}

__device__ __forceinline__ float bf2f(unsigned short u) {
  union { unsigned u; float f; } a; a.u = ((unsigned)u) << 16;
  return a.f;
}

// L2-normalize+bf16-cast vis (B*N rows) and txt (B*M rows), one wave per row;
// trailing 4 blocks compute masksum[b]; first trailing block also zeroes the
// sink barrier counters (stream order guarantees visibility to sink_fin).
__global__ __launch_bounds__(256) void prep_kernel(const float* __restrict__ vis,
                                                   const float* __restrict__ txt,
                                                   const float* __restrict__ mask,
                                                   unsigned short* __restrict__ xb,
                                                   unsigned short* __restrict__ yb,
                                                   float* __restrict__ masksum,
                                                   int* __restrict__ ctr) {
  const int bid = blockIdx.x;
  const int lane = threadIdx.x & 63;
  if (bid < NROWS / 4) {
    int wave = bid * 4 + (threadIdx.x >> 6);
    const float* src;
    unsigned short* dst;
    if (wave < B_ * N_) {
      src = vis + (size_t)wave * D_;
      dst = xb + (size_t)wave * D_;
    } else {
      int r = wave - B_ * N_;
      src = txt + (size_t)r * D_;
      dst = yb + (size_t)r * D_;
    }
    float4 v[4];
    float s = 0.f;
#pragma unroll
    for (int it = 0; it < 4; ++it) {
      v[it] = *(const float4*)&src[it * 256 + lane * 4];
      s += v[it].x * v[it].x + v[it].y * v[it].y + v[it].z * v[it].z + v[it].w * v[it].w;
    }
    s = wave_reduce(s);
    s = __shfl(s, 0, 64);
    float inv = rsqrtf(s + 1e-12f);
#pragma unroll
    for (int it = 0; it < 4; ++it) {
      ushort4 pk;
      pk.x = f2bf(v[it].x * inv);
      pk.y = f2bf(v[it].y * inv);
      pk.z = f2bf(v[it].z * inv);
      pk.w = f2bf(v[it].w * inv);
      *(ushort4*)&dst[it * 256 + lane * 4] = pk;
    }
  } else {
    if (bid == NROWS / 4 && threadIdx.x < 96) ctr[threadIdx.x] = 0;
    int b = (bid - NROWS / 4) * 4 + (threadIdx.x >> 6);  // 0..15
    float4 mv = *(const float4*)&mask[b * M_ + lane * 4];
    float s = wave_reduce(mv.x + mv.y + mv.z + mv.w);
    if (lane == 0) masksum[b] = s;
  }
}

// One launch, two block roles:
//   blocks 0..575:    K[b,m,n] = bf16(exp(10*(dot(y,x)-1))), 64x64 MFMA tile
//                     (verbatim verified body; compute/LDS-bound)
//   blocks 576..2879: SL = sum_h log(student+EPS), 1 float4/thread
//                     (HBM-bound; overlaps the MFMA blocks)
__global__ __launch_bounds__(256) void gemm_sumlog_kernel(
    const unsigned short* __restrict__ xb, const unsigned short* __restrict__ yb,
    const float* __restrict__ student, unsigned short* __restrict__ Kw,
    float* __restrict__ SL) {
  __shared__ unsigned short As[64][LDS_STRIDE];  // y rows (m)
  __shared__ unsigned short Bs[64][LDS_STRIDE];  // x rows (n)

  if (blockIdx.x >= GEMM_BLOCKS) {
    const int unit = (blockIdx.x - GEMM_BLOCKS) * 256 + threadIdx.x;  // 0..589823
    const int b = unit / (M_ * N_ / 4);
    const int cb = unit - b * (M_ * N_ / 4);
    const float* st = student + (size_t)b * H_ * M_ * N_ + (size_t)cb * 4;
    float4 acc = {0.f, 0.f, 0.f, 0.f};
#pragma unroll
    for (int h = 0; h < H_; ++h) {
      float4 s4 = *(const float4*)&st[(size_t)h * M_ * N_];
      acc.x += __logf(s4.x + EPS_);
      acc.y += __logf(s4.y + EPS_);
      acc.z += __logf(s4.z + EPS_);
      acc.w += __logf(s4.w + EPS_);
    }
    *(float4*)&SL[(size_t)b * M_ * N_ + (size_t)cb * 4] = acc;
    return;
  }

  const int tile = blockIdx.x;
  const int b = tile / 36;
  const int rem = tile - b * 36;
  const int m0 = (rem / 9) * 64;
  const int n0 = (rem - (rem / 9) * 9) * 64;
  const unsigned short* Y = yb + (size_t)b * M_ * D_;
  const unsigned short* X = xb + (size_t)b * N_ * D_;
  const int t = threadIdx.x;
  const int lane = t & 63;
  const int w = t >> 6;
  const int wm = (w & 1) * 32;
  const int wn = (w >> 1) * 32;
  const int lr = t >> 3;           // 0..31 staging row
  const int lc = (t & 7) * 8;      // staging col (bf16 units, 16B chunks)
  const int fr = lane & 15;        // fragment row within 16
  const int fk = (lane >> 4) * 8;  // fragment k offset

  f32x4 acc[2][2] = {};
  for (int k0 = 0; k0 < D_; k0 += BK) {
#pragma unroll
    for (int p = 0; p < 2; ++p) {
      *(uint4*)&As[lr + 32 * p][lc] = *(const uint4*)&Y[(size_t)(m0 + lr + 32 * p) * D_ + k0 + lc];
      *(uint4*)&Bs[lr + 32 * p][lc] = *(const uint4*)&X[(size_t)(n0 + lr + 32 * p) * D_ + k0 + lc];
    }
    __syncthreads();
#pragma unroll
    for (int ks = 0; ks < BK; ks += 32) {
      bf16x8 a[2], bfr[2];
#pragma unroll
      for (int i = 0; i < 2; ++i) {
        a[i] = *(const bf16x8*)&As[wm + i * 16 + fr][ks + fk];
        bfr[i] = *(const bf16x8*)&Bs[wn + i * 16 + fr][ks + fk];
      }
#pragma unroll
      for (int i = 0; i < 2; ++i)
#pragma unroll
        for (int j = 0; j < 2; ++j)
          acc[i][j] = __builtin_amdgcn_mfma_f32_16x16x32_bf16(a[i], bfr[j], acc[i][j], 0, 0, 0);
    }
    __syncthreads();
  }

  // C/D layout: m = (lane>>4)*4 + reg, n = lane&15
  const int cm = (lane >> 4) * 4;
  const int cn = lane & 15;
#pragma unroll
  for (int i = 0; i < 2; ++i)
#pragma unroll
    for (int j = 0; j < 2; ++j)
#pragma unroll
      for (int rg = 0; rg < 4; ++rg) {
        int m = m0 + wm + i * 16 + cm + rg;
        int n = n0 + wn + j * 16 + cn;
        Kw[((size_t)b * M_ + m) * N_ + n] = f2bf(expf(10.f * (acc[i][j][rg] - 1.f)));
      }
}

// 64 persistent blocks: block (b,q) owns rows q*64..q*64+63 of batch b with its
// K slab in LDS (loaded once). 5 Sinkhorn iterations:
//   u-step: local (exact 9-term k-order lane sum + shfl tree, row-owned)
//   v-step: exact quarter partials (m ascending within quarter) -> global,
//           4-block per-batch atomic barrier (double-buffered), then every
//           block re-combines quarters in exact q-order.
// Then finloss for the block's own 64 rows (exact 144-thread/4-wave pattern),
// and the last-finished block performs the exact final reduction.
__global__ __launch_bounds__(256) void sink_fin_kernel(
    const unsigned short* __restrict__ Kw, const float* __restrict__ SL,
    const float* __restrict__ mask, const float* __restrict__ msum,
    float* __restrict__ vp_g, int* __restrict__ ctr,
    float* __restrict__ partial, float* __restrict__ out) {
  __shared__ unsigned short slab[64][N_];   // 73728 B
  __shared__ float v_s[N_];
  __shared__ float u_s[64];
  __shared__ float nu_s[64];
  __shared__ float red[2][4];
  __shared__ float redr[4];
  __shared__ int lastflag;

  const int t = threadIdx.x;
  const int lane = t & 63;
  const int w = t >> 6;                 // wave 0..3
  const int b = blockIdx.x >> 2;
  const int q = blockIdx.x & 3;
  const int row0 = q * 64;

  // Load K slab (coalesced 16B chunks, 72 per row).
  const unsigned short* Kbase = Kw + ((size_t)b * M_ + row0) * N_;
  for (int i = t; i < 64 * 72; i += 256) {
    const int r = i / 72;
    const int c8 = (i - r * 72) * 8;
    *(uint4*)&slab[r][c8] = *(const uint4*)&Kbase[(size_t)r * N_ + c8];
  }
  if (t < 64) nu_s[t] = mask[b * M_ + row0 + t] / (msum[b] + EPS_);
  for (int n = t; n < N_; n += 256) v_s[n] = 1.f;
  __syncthreads();

  float* vp_b = vp_g + (size_t)b * 2 * 4 * N_;   // [2][4][N_] per batch

  for (int it = 0; it < 5; ++it) {
    // ---- u-step: wave w rows w*16..w*16+15 (k*1.0 fma == k+s, bit-exact
    // with the v==1 first step of the verified kernel) ----
#pragma unroll 2
    for (int r = 0; r < 16; ++r) {
      const int m = w * 16 + r;
      float s = 0.f;
#pragma unroll
      for (int k = 0; k < 9; ++k) s += bf2f(slab[m][lane + 64 * k]) * v_s[lane + 64 * k];
      s = wave_reduce(s);
      if (lane == 0) u_s[m] = powf(nu_s[m] / (s + EPS_), FI_);
    }
    __syncthreads();

    // ---- v-step quarter partials: thread t cols {t, t+256, t+512} ----
    const int par = it & 1;
    float* vp_out = vp_b + (size_t)(par * 4 + q) * N_;
    for (int c = t; c < N_; c += 256) {
      float s = 0.f;
#pragma unroll 8
      for (int m = 0; m < 64; ++m) s += bf2f(slab[m][c]) * u_s[m];
      vp_out[c] = s;
    }
    __syncthreads();   // all vp writes issued+complete (vmcnt drained) per wave

    // ---- per-batch 4-block barrier (device scope) ----
    if (t == 0) {
      __threadfence();
      __hip_atomic_fetch_add(&ctr[b * 5 + it], 1, __ATOMIC_RELEASE,
                             __HIP_MEMORY_SCOPE_AGENT);
      while (__hip_atomic_load(&ctr[b * 5 + it], __ATOMIC_ACQUIRE,
                               __HIP_MEMORY_SCOPE_AGENT) < 4)
        __builtin_amdgcn_s_sleep(1);
    }
    __syncthreads();
    __threadfence();   // acquire: invalidate stale cached vp lines

    // ---- combine quarters in exact q-order, recompute v locally ----
    const float* vp0 = vp_b + (size_t)par * 4 * N_;
    for (int n = t; n < N_; n += 256) {
      float tot = ((vp0[n] + vp0[N_ + n]) + vp0[2 * N_ + n]) + vp0[3 * N_ + n];
      v_s[n] = powf((1.f / (float)N_) / (tot + EPS_), FI_);
    }
    __syncthreads();
  }

  // ---- finloss for this block's 64 rows (exact verified pattern) ----
  for (int r = 0; r < 64; ++r) {
    const int row = b * M_ + row0 + r;
    float s1 = 0.f, s2 = 0.f;
    if (t < 144) {
      ushort4 k4 = *(const ushort4*)&slab[r][t * 4];
      float4 v4 = *(const float4*)&v_s[t * 4];
      float4 sl4 = *(const float4*)&SL[(size_t)row * N_ + t * 4];
      float kv0 = bf2f(k4.x) * v4.x, kv1 = bf2f(k4.y) * v4.y;
      float kv2 = bf2f(k4.z) * v4.z, kv3 = bf2f(k4.w) * v4.w;
      s1 = kv0 + kv1 + kv2 + kv3;
      s2 = kv0 * sl4.x + kv1 * sl4.y + kv2 * sl4.z + kv3 * sl4.w;
    }
    s1 = wave_reduce(s1);
    s2 = wave_reduce(s2);
    if ((t & 63) == 0) { red[0][t >> 6] = s1; red[1][t >> 6] = s2; }
    __syncthreads();
    if (t == 0) {
      float S1 = red[0][0] + red[0][1] + red[0][2] + red[0][3];
      float S2 = red[1][0] + red[1][1] + red[1][2] + red[1][3];
      partial[row] = -mask[row] * S2 / ((S1 + EPS_) * (float)(B_ * H_ * M_));
    }
    __syncthreads();
  }

  // ---- last-done block performs the exact final reduction ----
  if (t == 0) {
    __threadfence();
    int fin = __hip_atomic_fetch_add(&ctr[80], 1, __ATOMIC_ACQ_REL,
                                     __HIP_MEMORY_SCOPE_AGENT);
    lastflag = (fin == 63);
  }
  __syncthreads();
  if (lastflag) {
    __threadfence();
    float s = 0.f;
    for (int i = t; i < B_ * M_; i += 256) s += partial[i];
    s = wave_reduce(s);
    if ((t & 63) == 0) redr[t >> 6] = s;
    __syncthreads();
    if (t == 0) out[0] = redr[0] + redr[1] + redr[2] + redr[3];
  }
}

extern "C" void kernel_launch(void* const* d_in, const int* in_sizes, int n_in,
                              void* d_out, int out_size, void* d_ws, size_t ws_size,
                              hipStream_t stream) {
  const float* student = (const float*)d_in[0];  // (B,H,M,N)
  const float* vis = (const float*)d_in[1];      // (B,N,D)
  const float* txt = (const float*)d_in[2];      // (B,M,D)
  const float* mask = (const float*)d_in[3];     // (B,M)
  float* out = (float*)d_out;

  char* p = (char*)d_ws;
  unsigned short* Kw = (unsigned short*)p; p += (size_t)B_ * M_ * N_ * 2;   // 4.7 MB
  unsigned short* xb = (unsigned short*)p; p += (size_t)B_ * N_ * D_ * 2;   // 18.9 MB
  unsigned short* yb = (unsigned short*)p; p += (size_t)B_ * M_ * D_ * 2;   // 8.4 MB
  float* SL = (float*)p;      p += (size_t)B_ * M_ * N_ * 4;                // 9.4 MB
  float* msum = (float*)p;    p += 256;                                     // 16 f
  float* partial = (float*)p; p += (size_t)B_ * M_ * 4;                     // 16 KB
  float* vp_g = (float*)p;    p += (size_t)B_ * 2 * 4 * N_ * 4;             // 288 KB
  int* ctr = (int*)p;         p += 96 * 4;

  prep_kernel<<<NROWS / 4 + 4, 256, 0, stream>>>(vis, txt, mask, xb, yb, msum, ctr);
  gemm_sumlog_kernel<<<GEMM_BLOCKS + SUMLOG_BLK, 256, 0, stream>>>(xb, yb, student, Kw, SL);
  sink_fin_kernel<<<B_ * 4, 256, 0, stream>>>(Kw, SL, mask, msum, vp_g, ctr, partial, out);
}